// Round 1
// baseline (270.593 us; speedup 1.0000x reference)
//
#include <hip/hip_runtime.h>
#include <math.h>

// Problem constants (fixed by setup_inputs): N=65536 rows, D=512, out = 1 float.
#define NROWS 65536
#define DIM   512

__device__ __forceinline__ unsigned bucket_of(float r) {
    // r in [0,1); mult by 2^16 is exact (exponent shift) -> monotone bucketing.
    unsigned b = (unsigned)(r * 65536.0f);
    return b > 65535u ? 65535u : b;
}

// --- norms of the two reference vectors -------------------------------------
__global__ void k_bnorm(const float* __restrict__ b2, const float* __restrict__ b3,
                        float* __restrict__ bn) {
    int lane = threadIdx.x;  // 64 threads
    float s2 = 0.f, s3 = 0.f;
    for (int k = lane; k < DIM; k += 64) {
        float v2 = b2[k]; s2 += v2 * v2;
        float v3 = b3[k]; s3 += v3 * v3;
    }
#pragma unroll
    for (int off = 32; off > 0; off >>= 1) {
        s2 += __shfl_xor(s2, off);
        s3 += __shfl_xor(s3, off);
    }
    if (lane == 0) { bn[0] = sqrtf(s2); bn[1] = sqrtf(s3); }
}

// --- per-row cosine sims -> e2/e3, fused ranking histogram ------------------
__global__ __launch_bounds__(256) void k_rows(
    const float* __restrict__ x, const float* __restrict__ b2,
    const float* __restrict__ b3, const float* __restrict__ ranking,
    const float* __restrict__ bn, float* __restrict__ e2, float* __restrict__ e3,
    unsigned* __restrict__ hist)
{
    const int row  = (int)((blockIdx.x * 256u + threadIdx.x) >> 6);  // wave per row
    const int lane = threadIdx.x & 63;
    const float4* xr  = (const float4*)(x + (size_t)row * DIM);
    const float4* b2v = (const float4*)b2;
    const float4* b3v = (const float4*)b3;
    float dot2 = 0.f, dot3 = 0.f, ss = 0.f;
#pragma unroll
    for (int k = 0; k < 2; ++k) {
        const int idx = lane + (k << 6);   // 128 float4 per row
        const float4 xv = xr[idx];
        const float4 u  = b2v[idx];
        const float4 w  = b3v[idx];
        dot2 += xv.x * u.x + xv.y * u.y + xv.z * u.z + xv.w * u.w;
        dot3 += xv.x * w.x + xv.y * w.y + xv.z * w.z + xv.w * w.w;
        ss   += xv.x * xv.x + xv.y * xv.y + xv.z * xv.z + xv.w * xv.w;
    }
#pragma unroll
    for (int off = 32; off > 0; off >>= 1) {
        dot2 += __shfl_xor(dot2, off);
        dot3 += __shfl_xor(dot3, off);
        ss   += __shfl_xor(ss, off);
    }
    if (lane == 0) {
        const float nx = sqrtf(ss);
        const float s2 = dot2 / fmaxf(nx * bn[0], 1e-8f);
        const float s3 = dot3 / fmaxf(nx * bn[1], 1e-8f);
        e2[row] = expf(s2);
        e3[row] = expf(s3);
        atomicAdd(&hist[bucket_of(ranking[row])], 1u);
    }
}

// --- exclusive scan of 65536-bin histogram (single block) -------------------
__global__ __launch_bounds__(1024) void k_scan_hist(const unsigned* __restrict__ hist,
                                                    unsigned* __restrict__ histScan) {
    __shared__ unsigned part[1024];
    const int t = threadIdx.x;
    const int base = t << 6;  // 64 bins per thread
    unsigned s = 0;
    for (int k = 0; k < 64; ++k) s += hist[base + k];
    part[t] = s;
    __syncthreads();
    for (int d = 1; d < 1024; d <<= 1) {
        unsigned add = (t >= d) ? part[t - d] : 0u;
        __syncthreads();
        part[t] += add;
        __syncthreads();
    }
    unsigned run = part[t] - s;  // exclusive offset for this thread's chunk
    for (int k = 0; k < 64; ++k) {
        histScan[base + k] = run;
        run += hist[base + k];
    }
    if (t == 1023) histScan[NROWS] = run;  // == NROWS
}

// --- scatter element indices into bucket slots ------------------------------
__global__ __launch_bounds__(256) void k_scatter(const float* __restrict__ ranking,
                                                 const unsigned* __restrict__ histScan,
                                                 unsigned* __restrict__ counter,
                                                 unsigned* __restrict__ sidx) {
    const int i = (int)(blockIdx.x * 256u + threadIdx.x);
    const float r = ranking[i];
    const unsigned b = bucket_of(r);
    const unsigned slot = histScan[b] + atomicAdd(&counter[b], 1u);
    sidx[slot] = i;
}

// --- exact rank within bucket, scatter e into ascending-ranking order -------
// Tie-break: higher original index first (matches reversed stable descending argsort).
__global__ __launch_bounds__(256) void k_rank(const float* __restrict__ ranking,
                                              const unsigned* __restrict__ histScan,
                                              const unsigned* __restrict__ sidx,
                                              const float* __restrict__ e2,
                                              const float* __restrict__ e3,
                                              float* __restrict__ se2,
                                              float* __restrict__ se3) {
    const int s = (int)(blockIdx.x * 256u + threadIdx.x);
    const unsigned i = sidx[s];
    const float r = ranking[i];
    const unsigned b = bucket_of(r);
    const unsigned start = histScan[b];
    const unsigned end   = histScan[b + 1];
    unsigned rank = start;
    for (unsigned m = start; m < end; ++m) {
        const unsigned j = sidx[m];
        const float rj = ranking[j];
        if (rj < r || (rj == r && j > i)) rank++;
    }
    se2[rank] = e2[i];
    se3[rank] = e3[i];
}

// --- prefix scan of sorted e2/e3 + sum of logs (single block) ---------------
__global__ __launch_bounds__(1024) void k_final(const float* __restrict__ se2,
                                                const float* __restrict__ se3,
                                                float* __restrict__ out) {
    __shared__ float p2s[1024];
    __shared__ float p3s[1024];
    __shared__ double lsum[1024];
    const int t = threadIdx.x;
    const int base = t << 6;  // 64 elements per thread
    float s2 = 0.f, s3 = 0.f;
    for (int k = 0; k < 64; ++k) { s2 += se2[base + k]; s3 += se3[base + k]; }
    p2s[t] = s2; p3s[t] = s3;
    __syncthreads();
    for (int d = 1; d < 1024; d <<= 1) {
        float a2 = (t >= d) ? p2s[t - d] : 0.f;
        float a3 = (t >= d) ? p3s[t - d] : 0.f;
        __syncthreads();
        p2s[t] += a2; p3s[t] += a3;
        __syncthreads();
    }
    const float tot2 = p2s[1023];
    const float tot3 = p3s[1023];
    float run2 = p2s[t] - s2;  // exclusive offset
    float run3 = p3s[t] - s3;
    double acc = 0.0;
    for (int k = 0; k < 64; ++k) {
        const int p = base + k;          // prefix length p+1 after adding
        run2 += se2[p];
        run3 += se3[p];
        if (p < NROWS - 1) {             // p = 1..N-1 prefixes only
            acc += (double)logf(run2) + (double)logf(run3);
        }
    }
    lsum[t] = acc;
    __syncthreads();
    for (int d = 512; d > 0; d >>= 1) {
        if (t < d) lsum[t] += lsum[t + d];
        __syncthreads();
    }
    if (t == 0) {
        const double loss =
            (double)(NROWS - 1) * ((double)logf(tot2) + (double)logf(tot3)) - lsum[0];
        out[0] = (float)loss;
    }
}

extern "C" void kernel_launch(void* const* d_in, const int* in_sizes, int n_in,
                              void* d_out, int out_size, void* d_ws, size_t ws_size,
                              hipStream_t stream) {
    const float* x  = (const float*)d_in[0];  // [N, D]
    const float* b2 = (const float*)d_in[1];  // [1, D]
    const float* b3 = (const float*)d_in[2];  // [1, D]
    const float* rk = (const float*)d_in[3];  // [N]

    // Workspace layout (4-byte units). Total = 8N + ~66 words ~= 2 MB.
    unsigned* hist     = (unsigned*)d_ws;
    unsigned* counter  = hist + NROWS;
    unsigned* histScan = counter + NROWS;        // N+1 used, padded to N+64
    float*    e2   = (float*)(histScan + NROWS + 64);
    float*    e3   = e2 + NROWS;
    unsigned* sidx = (unsigned*)(e3 + NROWS);
    float*    se2  = (float*)(sidx + NROWS);
    float*    se3  = se2 + NROWS;
    float*    bn   = se3 + NROWS;

    // hist + counter (adjacent) must be zero each call (ws is poisoned 0xAA).
    hipMemsetAsync(hist, 0, 2 * NROWS * sizeof(unsigned), stream);

    k_bnorm<<<1, 64, 0, stream>>>(b2, b3, bn);
    k_rows<<<NROWS / 4, 256, 0, stream>>>(x, b2, b3, rk, bn, e2, e3, hist);
    k_scan_hist<<<1, 1024, 0, stream>>>(hist, histScan);
    k_scatter<<<NROWS / 256, 256, 0, stream>>>(rk, histScan, counter, sidx);
    k_rank<<<NROWS / 256, 256, 0, stream>>>(rk, histScan, sidx, e2, e3, se2, se3);
    k_final<<<1, 1024, 0, stream>>>(se2, se3, (float*)d_out);
}